// Round 14
// baseline (250.382 us; speedup 1.0000x reference)
//
#include <hip/hip_runtime.h>
#include <hip/hip_bf16.h>

typedef __attribute__((ext_vector_type(8))) short s8v;
typedef __attribute__((ext_vector_type(4))) float f4v;
typedef unsigned short us4 __attribute__((ext_vector_type(4)));

#define NB 8192
#define ND 1024
#define NH 8
#define NU 1365
#define NUP 1408
#define GK 384
#define GN 512
static const size_t BD = (size_t)NB * ND;

// workspace layout (bytes)
#define WS_AG   ((size_t)0)          // bf16 [8192][3072]  A-operand for gates
#define WS_G    ((size_t)50331648)   // bf16 [8192][1408]  gated-MLP intermediate
#define WS_HBF  ((size_t)73400320)   // bf16 [8192][1024]  h_t
#define WS_WG   ((size_t)90177536)   // bf16 [4096][384]   gate weights, gate-interleaved cols
#define WS_ULR  ((size_t)93323264)   // bf16 [2816][1024]  interleaved upL/upR^T (16-col groups)
#define WS_DWNT ((size_t)99090432)   // bf16 [1024][1408]  down^T padded

__device__ __forceinline__ void gload16(const void* g, void* l) {
  __builtin_amdgcn_global_load_lds((const __attribute__((address_space(1))) void*)g,
                                   (__attribute__((address_space(3))) void*)l, 16, 0, 0);
}
__device__ __forceinline__ unsigned short tobf(float f) {
  unsigned int u = __float_as_uint(f);
  unsigned int r = (u + 0x7FFFu + ((u >> 16) & 1u)) >> 16;
  return (unsigned short)r;
}
__device__ __forceinline__ float frcp(float x) { return __builtin_amdgcn_rcpf(x); }
__device__ __forceinline__ float fsigm(float x) { return frcp(1.f + __expf(-x)); }
__device__ __forceinline__ float ftanh(float x) {
  float e = __expf(2.f * x);
  return 1.f - 2.f * frcp(e + 1.f);
}
__device__ __forceinline__ f4v mfma16(s8v a, s8v b, f4v c) {
  return __builtin_amdgcn_mfma_f32_16x16x32_bf16(a, b, c, 0, 0, 0);
}

// ---------------- fused prep (weights) + norm_conv (LN+conv+SiLU) ----------------
__global__ __launch_bounds__(256) void prep_norm(
    const float* __restrict__ W, const float* __restrict__ R,
    const float* __restrict__ upl, const float* __restrict__ upr,
    const float* __restrict__ dwn,
    const float* __restrict__ x, const float* __restrict__ hp,
    const float* __restrict__ lg, const float* __restrict__ lb,
    const float* __restrict__ cw, const float* __restrict__ cb,
    unsigned short* __restrict__ Wg, unsigned short* __restrict__ ULR,
    unsigned short* __restrict__ Dt, unsigned short* __restrict__ Ag) {
  if (blockIdx.x < 23040) {
    long long idx = (long long)blockIdx.x * 256 + threadIdx.x;
    const long long N1 = (long long)4096 * GK;
    const long long N3 = (long long)2 * NUP * ND;
    const long long N2 = (long long)NUP * ND;
    if (idx < N1) {
      int c = (int)(idx / GK), k = (int)(idx % GK);
      int j = c & 15, g = (c >> 4) & 3, cgrp = (c >> 6) & 7, h = c >> 9;
      int o = cgrp * 16 + j;
      float v = 0.f;
      if (k < 128) {
        if (g == 0 || g == 3) v = W[(((size_t)g * NH + h) * 128 + k) * 128 + o];
      } else if (k < 256) {
        if (g == 1 || g == 2) v = W[(((size_t)g * NH + h) * 128 + (k - 128)) * 128 + o];
      } else {
        v = R[(((size_t)g * NH + h) * 128 + (k - 256)) * 128 + o];
      }
      Wg[idx] = tobf(v);
      return;
    }
    idx -= N1;
    if (idx < N3) {
      int r = (int)(idx / ND), k = (int)(idx % ND);
      int o = (r >> 4) & 1;
      int gcol = (r >> 5) * 16 + (r & 15);
      float v = 0.f;
      if (gcol < NU) v = o ? upr[(size_t)k * NU + gcol] : upl[(size_t)k * NU + gcol];
      ULR[idx] = tobf(v);
      return;
    }
    idx -= N3;
    if (idx < N2) { int n = (int)(idx / NUP), k = (int)(idx % NUP);
      Dt[idx] = (k < NU) ? tobf(dwn[(size_t)k * ND + n]) : 0; }
    return;
  }
  // ---- norm_conv part ----
  const int b = blockIdx.x - 23040, tid = threadIdx.x;
  const int lane = tid & 63, wv = tid >> 6;
  __shared__ float xs[1024];
  __shared__ float red[8];
  const int d0 = tid * 4;
  float4 xv = *(const float4*)(x + (size_t)b * ND + d0);
  float s = xv.x + xv.y + xv.z + xv.w;
  float ss = xv.x * xv.x + xv.y * xv.y + xv.z * xv.z + xv.w * xv.w;
#pragma unroll
  for (int o = 32; o; o >>= 1) { s += __shfl_down(s, o); ss += __shfl_down(ss, o); }
  if (lane == 0) { red[wv] = s; red[4 + wv] = ss; }
  __syncthreads();
  float S = red[0] + red[1] + red[2] + red[3];
  float SS = red[4] + red[5] + red[6] + red[7];
  float mu = S * (1.f / ND);
  float var = SS * (1.f / ND) - mu * mu;
  float rstd = rsqrtf(var + 1e-5f);
  float xn[4];
#pragma unroll
  for (int t = 0; t < 4; ++t) {
    float xx = (&xv.x)[t];
    xn[t] = (xx - mu) * rstd * lg[d0 + t] + lb[d0 + t];
    xs[d0 + t] = xn[t];
  }
  __syncthreads();
  float w0 = cw[0], w1 = cw[1], w2 = cw[2], w3 = cw[3], cbv = cb[0];
  float cv[4];
#pragma unroll
  for (int t = 0; t < 4; ++t) {
    int d = d0 + t;
    float a = cbv + w3 * xs[d];
    if (d >= 1) a += w2 * xs[d - 1];
    if (d >= 2) a += w1 * xs[d - 2];
    if (d >= 3) a += w0 * xs[d - 3];
    cv[t] = a * fsigm(a);
  }
  float4 hv = *(const float4*)(hp + (size_t)b * ND + d0);
  const int h = d0 >> 7, j = d0 & 127;
  us4 px, pc, ph;
#pragma unroll
  for (int t = 0; t < 4; ++t) { px[t] = tobf((&xv.x)[t]); pc[t] = tobf(cv[t]); ph[t] = tobf((&hv.x)[t]); }
  size_t base = (size_t)b * 3072 + (size_t)h * 384 + j;
  *(us4*)(Ag + base) = px;
  *(us4*)(Ag + base + 128) = pc;
  *(us4*)(Ag + base + 256) = ph;
}

// ---------------- fused gate GEMM + sLSTM state update (R10-best, 3D grid) ----------------
__global__ __launch_bounds__(256) void gate_fused(
    const unsigned short* __restrict__ Ag, const unsigned short* __restrict__ Wg,
    const float* __restrict__ bW, const float* __restrict__ bR,
    const float* __restrict__ cp, const float* __restrict__ np_,
    const float* __restrict__ mp,
    float* __restrict__ dout, unsigned short* __restrict__ Hb) {
  __shared__ short As[128 * 32];   // 8KB
  __shared__ short Bs[128 * 32];   // 8KB
  const int tid = threadIdx.x, lane = tid & 63, wv = tid >> 6;
  const int wm = wv >> 1, wn = wv & 1;
  const int row0 = blockIdx.x * 128;
  const int p = blockIdx.y;
  const int h = blockIdx.z;
  const int srow = wv * 32 + (lane >> 2), scol = (lane & 3) * 8;
  const unsigned short* At = Ag + (size_t)h * 384;
  const unsigned short* Bt = Wg + ((size_t)h * 512 + (size_t)p * 128) * GK;
  const int cgrp = p * 2 + wn;
  const int gcol = h * 128 + cgrp * 16 + (lane & 15);
  float pc_[16], pn_[16], pm_[16];
#pragma unroll
  for (int m = 0; m < 4; ++m)
#pragma unroll
    for (int r = 0; r < 4; ++r) {
      const size_t idx = (size_t)(row0 + wm * 64 + m * 16 + (lane >> 4) * 4 + r) * ND + gcol;
      pc_[m * 4 + r] = cp[idx];
      pn_[m * 4 + r] = np_[idx];
      pm_[m * 4 + r] = mp[idx];
    }
  f4v acc[4][4] = {};
#pragma unroll
  for (int kt = 0; kt < 12; ++kt) {
    const int k0 = kt * 32;
    gload16(At + (size_t)(row0 + srow) * 3072 + k0 + scol, (char*)As + wv * 2048);
    gload16(At + (size_t)(row0 + srow + 16) * 3072 + k0 + scol, (char*)As + wv * 2048 + 1024);
    gload16(Bt + (size_t)srow * GK + k0 + scol, (char*)Bs + wv * 2048);
    gload16(Bt + (size_t)(srow + 16) * GK + k0 + scol, (char*)Bs + wv * 2048 + 1024);
    __syncthreads();
    s8v a[4];
#pragma unroll
    for (int m = 0; m < 4; ++m)
      a[m] = *(const s8v*)&As[(wm * 64 + m * 16 + (lane & 15)) * 32 + (lane >> 4) * 8];
#pragma unroll
    for (int g = 0; g < 4; ++g) {
      const bool active = (kt >= 8) || (kt < 4 ? (g == 0 || g == 3) : (g == 1 || g == 2));
      if (active) {
        s8v b = *(const s8v*)&Bs[(wn * 64 + g * 16 + (lane & 15)) * 32 + (lane >> 4) * 8];
#pragma unroll
        for (int m = 0; m < 4; ++m) acc[m][g] = mfma16(a[m], b, acc[m][g]);
      }
    }
    __syncthreads();
  }
  const float Bz = bW[gcol] + bR[gcol];
  const float Bi = bW[ND + gcol] + bR[ND + gcol];
  const float Bf = bW[2 * ND + gcol] + bR[2 * ND + gcol];
  const float Bo = bW[3 * ND + gcol] + bR[3 * ND + gcol];
#pragma unroll
  for (int m = 0; m < 4; ++m) {
    const int rbase = row0 + wm * 64 + m * 16 + (lane >> 4) * 4;
#pragma unroll
    for (int r = 0; r < 4; ++r) {
      const int e = m * 4 + r;
      const size_t idx = (size_t)(rbase + r) * ND + gcol;
      float zt = ftanh(acc[m][0][r] + Bz);
      float it = acc[m][1][r] + Bi;
      float ft = acc[m][2][r] + Bf;
      float ot = fsigm(acc[m][3][r] + Bo);
      float mv = pm_[e];
      float mt = fmaxf(ft + mv, it);
      float ii = __expf(it - mt);
      float ff = __expf(ft + mv - mt);
      float ct = ff * pc_[e] + ii * zt;
      float nt = ff * pn_[e] + ii;
      float ht = ot * ct * frcp(nt);
      dout[BD + idx] = ht;
      dout[2 * BD + idx] = ct;
      dout[3 * BD + idx] = nt;
      dout[4 * BD + idx] = mt;
      Hb[idx] = tobf(ht);
    }
  }
}

// ---------------- up GEMM with interleaved L/R B; fused glu epilogue -> bf16 G ----------------
__global__ __launch_bounds__(256) void up_gemm(
    const unsigned short* __restrict__ A, const unsigned short* __restrict__ ULR,
    const float* __restrict__ lbias, const float* __restrict__ rbias,
    unsigned short* __restrict__ G) {
  __shared__ short As[4096];
  __shared__ short Bs[4096];
  const int tid = threadIdx.x, lane = tid & 63, wv = tid >> 6;
  const int wm = wv >> 1, wn = wv & 1;
  const int bid = blockIdx.x;
  const int swz = (bid & 7) * 176 + (bid >> 3);   // 1408 = 8*176, bijective
  const int row0 = (swz / 22) * 128, n0 = (swz % 22) * 128;
  const int srow = wv * 32 + (lane >> 2), scol = (lane & 3) * 8;
  f4v acc[4][4] = {};
  for (int kt = 0; kt < 32; ++kt) {
    const int k0 = kt * 32;
    gload16(A + (size_t)(row0 + srow) * 1024 + k0 + scol, (char*)As + wv * 2048);
    gload16(A + (size_t)(row0 + srow + 16) * 1024 + k0 + scol, (char*)As + wv * 2048 + 1024);
    gload16(ULR + (size_t)(n0 + srow) * 1024 + k0 + scol, (char*)Bs + wv * 2048);
    gload16(ULR + (size_t)(n0 + srow + 16) * 1024 + k0 + scol, (char*)Bs + wv * 2048 + 1024);
    __syncthreads();
    s8v a[4], b[4];
#pragma unroll
    for (int m = 0; m < 4; ++m) a[m] = *(const s8v*)&As[(wm * 64 + m * 16 + (lane & 15)) * 32 + (lane >> 4) * 8];
#pragma unroll
    for (int n = 0; n < 4; ++n) b[n] = *(const s8v*)&Bs[(wn * 64 + n * 16 + (lane & 15)) * 32 + (lane >> 4) * 8];
#pragma unroll
    for (int m = 0; m < 4; ++m)
#pragma unroll
      for (int n = 0; n < 4; ++n) acc[m][n] = mfma16(a[m], b[n], acc[m][n]);
    __syncthreads();
  }
  const int gb = (n0 >> 1) + wn * 32;
#pragma unroll
  for (int m = 0; m < 4; ++m) {
    const int row = row0 + wm * 64 + m * 16 + (lane >> 4) * 4;
#pragma unroll
    for (int p = 0; p < 2; ++p) {
      const int gcol = gb + p * 16 + (lane & 15);
      const bool ok = gcol < NU;
      const float bl_ = ok ? lbias[gcol] : 0.f;
      const float br_ = ok ? rbias[gcol] : 0.f;
#pragma unroll
      for (int r = 0; r < 4; ++r) {
        float L = acc[m][2 * p][r] + bl_;
        float Rv = acc[m][2 * p + 1][r] + br_;
        float ge = 0.5f * Rv * (1.f + erff(Rv * 0.70710678118654752f));
        G[(size_t)(row + r) * NUP + gcol] = ok ? tobf(L * ge) : (unsigned short)0;
      }
    }
  }
}

// ---------------- down GEMM: G @ down^T + bias -> output (1-phase) ----------------
__global__ __launch_bounds__(256) void down_gemm(
    const unsigned short* __restrict__ A, const unsigned short* __restrict__ Bt,
    const float* __restrict__ dbias, float* __restrict__ out) {
  __shared__ short As[4096];
  __shared__ short Bs[4096];
  const int tid = threadIdx.x, lane = tid & 63, wv = tid >> 6;
  const int wm = wv >> 1, wn = wv & 1;
  const int bid = blockIdx.x;
  const int swz = (bid & 7) * 64 + (bid >> 3);    // 512 = 8*64, bijective
  const int row0 = (swz >> 3) * 128, n0 = (swz & 7) * 128;
  const int srow = wv * 32 + (lane >> 2), scol = (lane & 3) * 8;
  f4v acc[4][4] = {};
  for (int kt = 0; kt < NUP / 32; ++kt) {
    const int k0 = kt * 32;
    gload16(A + (size_t)(row0 + srow) * NUP + k0 + scol, (char*)As + wv * 2048);
    gload16(A + (size_t)(row0 + srow + 16) * NUP + k0 + scol, (char*)As + wv * 2048 + 1024);
    gload16(Bt + (size_t)(n0 + srow) * NUP + k0 + scol, (char*)Bs + wv * 2048);
    gload16(Bt + (size_t)(n0 + srow + 16) * NUP + k0 + scol, (char*)Bs + wv * 2048 + 1024);
    __syncthreads();
    s8v a[4], b[4];
#pragma unroll
    for (int m = 0; m < 4; ++m) a[m] = *(const s8v*)&As[(wm * 64 + m * 16 + (lane & 15)) * 32 + (lane >> 4) * 8];
#pragma unroll
    for (int n = 0; n < 4; ++n) b[n] = *(const s8v*)&Bs[(wn * 64 + n * 16 + (lane & 15)) * 32 + (lane >> 4) * 8];
#pragma unroll
    for (int m = 0; m < 4; ++m)
#pragma unroll
      for (int n = 0; n < 4; ++n) acc[m][n] = mfma16(a[m], b[n], acc[m][n]);
    __syncthreads();
  }
#pragma unroll
  for (int m = 0; m < 4; ++m) {
    const int row = row0 + wm * 64 + m * 16 + (lane >> 4) * 4;
#pragma unroll
    for (int n = 0; n < 4; ++n) {
      const int col = n0 + wn * 64 + n * 16 + (lane & 15);
      const float bias = dbias[col];
#pragma unroll
      for (int r = 0; r < 4; ++r)
        out[(size_t)(row + r) * ND + col] = acc[m][n][r] + bias;
    }
  }
}

extern "C" void kernel_launch(void* const* d_in, const int* in_sizes, int n_in,
                              void* d_out, int out_size, void* d_ws, size_t ws_size,
                              hipStream_t stream) {
  const float* x    = (const float*)d_in[0];
  const float* hp   = (const float*)d_in[1];
  const float* cp   = (const float*)d_in[2];
  const float* np_  = (const float*)d_in[3];
  const float* mp   = (const float*)d_in[4];
  const float* lg   = (const float*)d_in[5];
  const float* lb   = (const float*)d_in[6];
  const float* cw   = (const float*)d_in[7];
  const float* cb   = (const float*)d_in[8];
  const float* W    = (const float*)d_in[9];
  const float* bW   = (const float*)d_in[10];
  const float* R    = (const float*)d_in[11];
  const float* bR   = (const float*)d_in[12];
  const float* upl  = (const float*)d_in[13];
  const float* uplb = (const float*)d_in[14];
  const float* upr  = (const float*)d_in[15];
  const float* uprb = (const float*)d_in[16];
  const float* dwn  = (const float*)d_in[17];
  const float* dwnb = (const float*)d_in[18];
  float* out = (float*)d_out;
  char* ws = (char*)d_ws;
  unsigned short* Ag  = (unsigned short*)(ws + WS_AG);
  unsigned short* G   = (unsigned short*)(ws + WS_G);
  unsigned short* Hb  = (unsigned short*)(ws + WS_HBF);
  unsigned short* Wg  = (unsigned short*)(ws + WS_WG);
  unsigned short* ULR = (unsigned short*)(ws + WS_ULR);
  unsigned short* Dt  = (unsigned short*)(ws + WS_DWNT);

  prep_norm<<<23040 + NB, 256, 0, stream>>>(W, R, upl, upr, dwn, x, hp, lg, lb, cw, cb,
                                            Wg, ULR, Dt, Ag);
  gate_fused<<<dim3(64, 4, 8), 256, 0, stream>>>(Ag, Wg, bW, bR, cp, np_, mp, out, Hb);
  up_gemm<<<1408, 256, 0, stream>>>(Hb, ULR, uplb, uprb, G);
  down_gemm<<<512, 256, 0, stream>>>(G, Dt, dwnb, out);
}

// Round 15
// 235.132 us; speedup vs baseline: 1.0649x; 1.0649x over previous
//
#include <hip/hip_runtime.h>
#include <hip/hip_bf16.h>

typedef __attribute__((ext_vector_type(8))) short s8v;
typedef __attribute__((ext_vector_type(4))) float f4v;
typedef unsigned short us4 __attribute__((ext_vector_type(4)));

#define NB 8192
#define ND 1024
#define NH 8
#define NU 1365
#define NUP 1408
#define GK 384
#define GN 512
static const size_t BD = (size_t)NB * ND;

// workspace layout (bytes)
#define WS_AG   ((size_t)0)          // bf16 [8192][3072]  A-operand for gates
#define WS_G    ((size_t)50331648)   // bf16 [8192][1408]  gated-MLP intermediate
#define WS_HBF  ((size_t)73400320)   // bf16 [8192][1024]  h_t
#define WS_WG   ((size_t)90177536)   // bf16 [4096][384]   gate weights, gate-interleaved cols
#define WS_ULR  ((size_t)93323264)   // bf16 [2816][1024]  interleaved upL/upR^T (16-col groups)
#define WS_DWNT ((size_t)99090432)   // bf16 [1024][1408]  down^T padded

__device__ __forceinline__ void gload16(const void* g, void* l) {
  __builtin_amdgcn_global_load_lds((const __attribute__((address_space(1))) void*)g,
                                   (__attribute__((address_space(3))) void*)l, 16, 0, 0);
}
__device__ __forceinline__ unsigned short tobf(float f) {
  unsigned int u = __float_as_uint(f);
  unsigned int r = (u + 0x7FFFu + ((u >> 16) & 1u)) >> 16;
  return (unsigned short)r;
}
__device__ __forceinline__ float frcp(float x) { return __builtin_amdgcn_rcpf(x); }
__device__ __forceinline__ float fsigm(float x) { return frcp(1.f + __expf(-x)); }
__device__ __forceinline__ float ftanh(float x) {
  float e = __expf(2.f * x);
  return 1.f - 2.f * frcp(e + 1.f);
}
__device__ __forceinline__ float fgelu(float x) {
  // tanh-approx gelu (PyTorch approximate='tanh'); |err| ~3e-3, fine vs 0.134 threshold
  float t = ftanh(0.7978845608f * (x + 0.044715f * x * x * x));
  return 0.5f * x * (1.f + t);
}
__device__ __forceinline__ f4v mfma16(s8v a, s8v b, f4v c) {
  return __builtin_amdgcn_mfma_f32_16x16x32_bf16(a, b, c, 0, 0, 0);
}

// ---------------- fused prep (weights) + norm_conv (LN+conv+SiLU) ----------------
__global__ __launch_bounds__(256) void prep_norm(
    const float* __restrict__ W, const float* __restrict__ R,
    const float* __restrict__ upl, const float* __restrict__ upr,
    const float* __restrict__ dwn,
    const float* __restrict__ x, const float* __restrict__ hp,
    const float* __restrict__ lg, const float* __restrict__ lb,
    const float* __restrict__ cw, const float* __restrict__ cb,
    unsigned short* __restrict__ Wg, unsigned short* __restrict__ ULR,
    unsigned short* __restrict__ Dt, unsigned short* __restrict__ Ag) {
  if (blockIdx.x < 23040) {
    long long idx = (long long)blockIdx.x * 256 + threadIdx.x;
    const long long N1 = (long long)4096 * GK;
    const long long N3 = (long long)2 * NUP * ND;
    const long long N2 = (long long)NUP * ND;
    if (idx < N1) {
      int c = (int)(idx / GK), k = (int)(idx % GK);
      int j = c & 15, g = (c >> 4) & 3, cgrp = (c >> 6) & 7, h = c >> 9;
      int o = cgrp * 16 + j;
      float v = 0.f;
      if (k < 128) {
        if (g == 0 || g == 3) v = W[(((size_t)g * NH + h) * 128 + k) * 128 + o];
      } else if (k < 256) {
        if (g == 1 || g == 2) v = W[(((size_t)g * NH + h) * 128 + (k - 128)) * 128 + o];
      } else {
        v = R[(((size_t)g * NH + h) * 128 + (k - 256)) * 128 + o];
      }
      Wg[idx] = tobf(v);
      return;
    }
    idx -= N1;
    if (idx < N3) {
      int r = (int)(idx / ND), k = (int)(idx % ND);
      int o = (r >> 4) & 1;
      int gcol = (r >> 5) * 16 + (r & 15);
      float v = 0.f;
      if (gcol < NU) v = o ? upr[(size_t)k * NU + gcol] : upl[(size_t)k * NU + gcol];
      ULR[idx] = tobf(v);
      return;
    }
    idx -= N3;
    if (idx < N2) { int n = (int)(idx / NUP), k = (int)(idx % NUP);
      Dt[idx] = (k < NU) ? tobf(dwn[(size_t)k * ND + n]) : 0; }
    return;
  }
  // ---- norm_conv part ----
  const int b = blockIdx.x - 23040, tid = threadIdx.x;
  const int lane = tid & 63, wv = tid >> 6;
  __shared__ float xs[1024];
  __shared__ float red[8];
  const int d0 = tid * 4;
  float4 xv = *(const float4*)(x + (size_t)b * ND + d0);
  float s = xv.x + xv.y + xv.z + xv.w;
  float ss = xv.x * xv.x + xv.y * xv.y + xv.z * xv.z + xv.w * xv.w;
#pragma unroll
  for (int o = 32; o; o >>= 1) { s += __shfl_down(s, o); ss += __shfl_down(ss, o); }
  if (lane == 0) { red[wv] = s; red[4 + wv] = ss; }
  __syncthreads();
  float S = red[0] + red[1] + red[2] + red[3];
  float SS = red[4] + red[5] + red[6] + red[7];
  float mu = S * (1.f / ND);
  float var = SS * (1.f / ND) - mu * mu;
  float rstd = rsqrtf(var + 1e-5f);
  float xn[4];
#pragma unroll
  for (int t = 0; t < 4; ++t) {
    float xx = (&xv.x)[t];
    xn[t] = (xx - mu) * rstd * lg[d0 + t] + lb[d0 + t];
    xs[d0 + t] = xn[t];
  }
  __syncthreads();
  float w0 = cw[0], w1 = cw[1], w2 = cw[2], w3 = cw[3], cbv = cb[0];
  float cv[4];
#pragma unroll
  for (int t = 0; t < 4; ++t) {
    int d = d0 + t;
    float a = cbv + w3 * xs[d];
    if (d >= 1) a += w2 * xs[d - 1];
    if (d >= 2) a += w1 * xs[d - 2];
    if (d >= 3) a += w0 * xs[d - 3];
    cv[t] = a * fsigm(a);
  }
  float4 hv = *(const float4*)(hp + (size_t)b * ND + d0);
  const int h = d0 >> 7, j = d0 & 127;
  us4 px, pc, ph;
#pragma unroll
  for (int t = 0; t < 4; ++t) { px[t] = tobf((&xv.x)[t]); pc[t] = tobf(cv[t]); ph[t] = tobf((&hv.x)[t]); }
  size_t base = (size_t)b * 3072 + (size_t)h * 384 + j;
  *(us4*)(Ag + base) = px;
  *(us4*)(Ag + base + 128) = pc;
  *(us4*)(Ag + base + 256) = ph;
}

// ---------------- fused gate GEMM + sLSTM state update (R10/R14-best, FROZEN) ----------------
__global__ __launch_bounds__(256) void gate_fused(
    const unsigned short* __restrict__ Ag, const unsigned short* __restrict__ Wg,
    const float* __restrict__ bW, const float* __restrict__ bR,
    const float* __restrict__ cp, const float* __restrict__ np_,
    const float* __restrict__ mp,
    float* __restrict__ dout, unsigned short* __restrict__ Hb) {
  __shared__ short As[128 * 32];   // 8KB
  __shared__ short Bs[128 * 32];   // 8KB
  const int tid = threadIdx.x, lane = tid & 63, wv = tid >> 6;
  const int wm = wv >> 1, wn = wv & 1;
  const int row0 = blockIdx.x * 128;
  const int p = blockIdx.y;
  const int h = blockIdx.z;
  const int srow = wv * 32 + (lane >> 2), scol = (lane & 3) * 8;
  const unsigned short* At = Ag + (size_t)h * 384;
  const unsigned short* Bt = Wg + ((size_t)h * 512 + (size_t)p * 128) * GK;
  const int cgrp = p * 2 + wn;
  const int gcol = h * 128 + cgrp * 16 + (lane & 15);
  float pc_[16], pn_[16], pm_[16];
#pragma unroll
  for (int m = 0; m < 4; ++m)
#pragma unroll
    for (int r = 0; r < 4; ++r) {
      const size_t idx = (size_t)(row0 + wm * 64 + m * 16 + (lane >> 4) * 4 + r) * ND + gcol;
      pc_[m * 4 + r] = cp[idx];
      pn_[m * 4 + r] = np_[idx];
      pm_[m * 4 + r] = mp[idx];
    }
  f4v acc[4][4] = {};
#pragma unroll
  for (int kt = 0; kt < 12; ++kt) {
    const int k0 = kt * 32;
    gload16(At + (size_t)(row0 + srow) * 3072 + k0 + scol, (char*)As + wv * 2048);
    gload16(At + (size_t)(row0 + srow + 16) * 3072 + k0 + scol, (char*)As + wv * 2048 + 1024);
    gload16(Bt + (size_t)srow * GK + k0 + scol, (char*)Bs + wv * 2048);
    gload16(Bt + (size_t)(srow + 16) * GK + k0 + scol, (char*)Bs + wv * 2048 + 1024);
    __syncthreads();
    s8v a[4];
#pragma unroll
    for (int m = 0; m < 4; ++m)
      a[m] = *(const s8v*)&As[(wm * 64 + m * 16 + (lane & 15)) * 32 + (lane >> 4) * 8];
#pragma unroll
    for (int g = 0; g < 4; ++g) {
      const bool active = (kt >= 8) || (kt < 4 ? (g == 0 || g == 3) : (g == 1 || g == 2));
      if (active) {
        s8v b = *(const s8v*)&Bs[(wn * 64 + g * 16 + (lane & 15)) * 32 + (lane >> 4) * 8];
#pragma unroll
        for (int m = 0; m < 4; ++m) acc[m][g] = mfma16(a[m], b, acc[m][g]);
      }
    }
    __syncthreads();
  }
  const float Bz = bW[gcol] + bR[gcol];
  const float Bi = bW[ND + gcol] + bR[ND + gcol];
  const float Bf = bW[2 * ND + gcol] + bR[2 * ND + gcol];
  const float Bo = bW[3 * ND + gcol] + bR[3 * ND + gcol];
#pragma unroll
  for (int m = 0; m < 4; ++m) {
    const int rbase = row0 + wm * 64 + m * 16 + (lane >> 4) * 4;
#pragma unroll
    for (int r = 0; r < 4; ++r) {
      const int e = m * 4 + r;
      const size_t idx = (size_t)(rbase + r) * ND + gcol;
      float zt = ftanh(acc[m][0][r] + Bz);
      float it = acc[m][1][r] + Bi;
      float ft = acc[m][2][r] + Bf;
      float ot = fsigm(acc[m][3][r] + Bo);
      float mv = pm_[e];
      float mt = fmaxf(ft + mv, it);
      float ii = __expf(it - mt);
      float ff = __expf(ft + mv - mt);
      float ct = ff * pc_[e] + ii * zt;
      float nt = ff * pn_[e] + ii;
      float ht = ot * ct * frcp(nt);
      dout[BD + idx] = ht;
      dout[2 * BD + idx] = ct;
      dout[3 * BD + idx] = nt;
      dout[4 * BD + idx] = mt;
      Hb[idx] = tobf(ht);
    }
  }
}

// ---------------- up GEMM, 1-phase BK=64 + both-sides XOR swizzle; fused GLU ----------------
// BK=64 halves barrier count (32 -> 16). LDS rows are 128B; the XOR swizzle
// (linear LDS dest + pre-swizzled GLOBAL source usrc=(lane&7)^(lane>>3), and
// read unit u=(kk*4+qr)^(lane&7)) spreads each ds_read_b128 over all 32 banks.
__global__ __launch_bounds__(256) void up_gemm(
    const unsigned short* __restrict__ A, const unsigned short* __restrict__ ULR,
    const float* __restrict__ lbias, const float* __restrict__ rbias,
    unsigned short* __restrict__ G) {
  __shared__ short As[128 * 64];   // 16KB
  __shared__ short Bs[128 * 64];   // 16KB
  const int tid = threadIdx.x, lane = tid & 63, wv = tid >> 6;
  const int wm = wv >> 1, wn = wv & 1;
  const int bid = blockIdx.x;
  const int swz = (bid & 7) * 176 + (bid >> 3);   // 1408 = 8*176, bijective
  const int row0 = (swz / 22) * 128, n0 = (swz % 22) * 128;
  const int sr = lane >> 3;                        // 0..7 row within 8-row group
  const int usrc = ((lane & 7) ^ sr) * 8;          // pre-swizzled source col (shorts)
  f4v acc[4][4] = {};
  for (int kt = 0; kt < 16; ++kt) {
    const int k0 = kt * 64;
#pragma unroll
    for (int q = 0; q < 4; ++q) {
      const int br = wv * 32 + q * 8;
      gload16(A + (size_t)(row0 + br + sr) * 1024 + k0 + usrc, (char*)As + br * 128);
      gload16(ULR + (size_t)(n0 + br + sr) * 1024 + k0 + usrc, (char*)Bs + br * 128);
    }
    __syncthreads();
#pragma unroll
    for (int kk = 0; kk < 2; ++kk) {
      const int u8 = (((kk * 4 + (lane >> 4)) ^ (lane & 7)) * 8);
      s8v a[4], b[4];
#pragma unroll
      for (int m = 0; m < 4; ++m)
        a[m] = *(const s8v*)&As[(wm * 64 + m * 16 + (lane & 15)) * 64 + u8];
#pragma unroll
      for (int n = 0; n < 4; ++n)
        b[n] = *(const s8v*)&Bs[(wn * 64 + n * 16 + (lane & 15)) * 64 + u8];
#pragma unroll
      for (int m = 0; m < 4; ++m)
#pragma unroll
        for (int n = 0; n < 4; ++n) acc[m][n] = mfma16(a[m], b[n], acc[m][n]);
    }
    __syncthreads();
  }
  const int gb = (n0 >> 1) + wn * 32;
#pragma unroll
  for (int m = 0; m < 4; ++m) {
    const int row = row0 + wm * 64 + m * 16 + (lane >> 4) * 4;
#pragma unroll
    for (int pp = 0; pp < 2; ++pp) {
      const int gcol = gb + pp * 16 + (lane & 15);
      const bool ok = gcol < NU;
      const float bl_ = ok ? lbias[gcol] : 0.f;
      const float br_ = ok ? rbias[gcol] : 0.f;
#pragma unroll
      for (int r = 0; r < 4; ++r) {
        float L = acc[m][2 * pp][r] + bl_;
        float Rv = acc[m][2 * pp + 1][r] + br_;
        G[(size_t)(row + r) * NUP + gcol] = ok ? tobf(L * fgelu(Rv)) : (unsigned short)0;
      }
    }
  }
}

// ---------------- down GEMM, 1-phase BK=64 + XOR swizzle: G @ down^T + bias ----------------
__global__ __launch_bounds__(256) void down_gemm(
    const unsigned short* __restrict__ A, const unsigned short* __restrict__ Bt,
    const float* __restrict__ dbias, float* __restrict__ out) {
  __shared__ short As[128 * 64];
  __shared__ short Bs[128 * 64];
  const int tid = threadIdx.x, lane = tid & 63, wv = tid >> 6;
  const int wm = wv >> 1, wn = wv & 1;
  const int bid = blockIdx.x;
  const int swz = (bid & 7) * 64 + (bid >> 3);    // 512 = 8*64, bijective
  const int row0 = (swz >> 3) * 128, n0 = (swz & 7) * 128;
  const int sr = lane >> 3;
  const int usrc = ((lane & 7) ^ sr) * 8;
  f4v acc[4][4] = {};
  for (int kt = 0; kt < NUP / 64; ++kt) {   // 22 iters
    const int k0 = kt * 64;
#pragma unroll
    for (int q = 0; q < 4; ++q) {
      const int br = wv * 32 + q * 8;
      gload16(A + (size_t)(row0 + br + sr) * NUP + k0 + usrc, (char*)As + br * 128);
      gload16(Bt + (size_t)(n0 + br + sr) * NUP + k0 + usrc, (char*)Bs + br * 128);
    }
    __syncthreads();
#pragma unroll
    for (int kk = 0; kk < 2; ++kk) {
      const int u8 = (((kk * 4 + (lane >> 4)) ^ (lane & 7)) * 8);
      s8v a[4], b[4];
#pragma unroll
      for (int m = 0; m < 4; ++m)
        a[m] = *(const s8v*)&As[(wm * 64 + m * 16 + (lane & 15)) * 64 + u8];
#pragma unroll
      for (int n = 0; n < 4; ++n)
        b[n] = *(const s8v*)&Bs[(wn * 64 + n * 16 + (lane & 15)) * 64 + u8];
#pragma unroll
      for (int m = 0; m < 4; ++m)
#pragma unroll
        for (int n = 0; n < 4; ++n) acc[m][n] = mfma16(a[m], b[n], acc[m][n]);
    }
    __syncthreads();
  }
#pragma unroll
  for (int m = 0; m < 4; ++m) {
    const int row = row0 + wm * 64 + m * 16 + (lane >> 4) * 4;
#pragma unroll
    for (int n = 0; n < 4; ++n) {
      const int col = n0 + wn * 64 + n * 16 + (lane & 15);
      const float bias = dbias[col];
#pragma unroll
      for (int r = 0; r < 4; ++r)
        out[(size_t)(row + r) * ND + col] = acc[m][n][r] + bias;
    }
  }
}

extern "C" void kernel_launch(void* const* d_in, const int* in_sizes, int n_in,
                              void* d_out, int out_size, void* d_ws, size_t ws_size,
                              hipStream_t stream) {
  const float* x    = (const float*)d_in[0];
  const float* hp   = (const float*)d_in[1];
  const float* cp   = (const float*)d_in[2];
  const float* np_  = (const float*)d_in[3];
  const float* mp   = (const float*)d_in[4];
  const float* lg   = (const float*)d_in[5];
  const float* lb   = (const float*)d_in[6];
  const float* cw   = (const float*)d_in[7];
  const float* cb   = (const float*)d_in[8];
  const float* W    = (const float*)d_in[9];
  const float* bW   = (const float*)d_in[10];
  const float* R    = (const float*)d_in[11];
  const float* bR   = (const float*)d_in[12];
  const float* upl  = (const float*)d_in[13];
  const float* uplb = (const float*)d_in[14];
  const float* upr  = (const float*)d_in[15];
  const float* uprb = (const float*)d_in[16];
  const float* dwn  = (const float*)d_in[17];
  const float* dwnb = (const float*)d_in[18];
  float* out = (float*)d_out;
  char* ws = (char*)d_ws;
  unsigned short* Ag  = (unsigned short*)(ws + WS_AG);
  unsigned short* G   = (unsigned short*)(ws + WS_G);
  unsigned short* Hb  = (unsigned short*)(ws + WS_HBF);
  unsigned short* Wg  = (unsigned short*)(ws + WS_WG);
  unsigned short* ULR = (unsigned short*)(ws + WS_ULR);
  unsigned short* Dt  = (unsigned short*)(ws + WS_DWNT);

  prep_norm<<<23040 + NB, 256, 0, stream>>>(W, R, upl, upr, dwn, x, hp, lg, lb, cw, cb,
                                            Wg, ULR, Dt, Ag);
  gate_fused<<<dim3(64, 4, 8), 256, 0, stream>>>(Ag, Wg, bW, bR, cp, np_, mp, out, Hb);
  up_gemm<<<1408, 256, 0, stream>>>(Hb, ULR, uplb, uprb, G);
  down_gemm<<<512, 256, 0, stream>>>(G, Dt, dwnb, out);
}